// Round 1
// baseline (159.230 us; speedup 1.0000x reference)
//
#include <hip/hip_runtime.h>
#include <hip/hip_bf16.h>

#define IDIM 64
#define RDIM 36
#define DDIM 1024
#define CDIM 64
#define WDIM 32
#define SMOOTH 9.0f
#define EPSF 1e-8f
#define ATS 52   // LDS row stride for 48-wide tiles: float4-aligned, conflict-light

typedef __bf16 bf16_t;
typedef __bf16 bf16x8 __attribute__((ext_vector_type(8)));
typedef __bf16 bf16x4 __attribute__((ext_vector_type(4)));
typedef float f32x4 __attribute__((ext_vector_type(4)));

#define MFMA16(a, b, c) __builtin_amdgcn_mfma_f32_16x16x32_bf16((a), (b), (c), 0, 0, 0)

// ---------- workspace layout (bytes) ----------
#define IMGSB_OFF 0
#define CAPSB_OFF (IDIM * RDIM * DDIM * 2)                 // 4718592
#define G_OFF     (CAPSB_OFF + CDIM * WDIM * DDIM * 2)     // 8912896
#define CAPN_OFF  (G_OFF + IDIM * RDIM * RDIM * 4)         // 9244672

// =====================================================================
// Kernel 1: fp32 -> bf16 conversion for imgs & caps, fused caps row norms.
// One wave per 1024-elem row. 2304 img rows + 2048 cap rows = 4352 waves.
// =====================================================================
__global__ __launch_bounds__(256) void prep_kernel(
    const float* __restrict__ imgs, const float* __restrict__ caps,
    bf16_t* __restrict__ imgsb, bf16_t* __restrict__ capsb,
    float* __restrict__ capnorm) {
  int wv = threadIdx.x >> 6, ln = threadIdx.x & 63;
  int row = blockIdx.x * 4 + wv;
  if (row < IDIM * RDIM) {
    const float4* src = (const float4*)(imgs + (size_t)row * DDIM);
    bf16x4* dst = (bf16x4*)(imgsb + (size_t)row * DDIM);
#pragma unroll
    for (int j = 0; j < 4; ++j) {
      int idx = j * 64 + ln;
      float4 v = src[idx];
      bf16x4 p;
      p[0] = (bf16_t)v.x; p[1] = (bf16_t)v.y; p[2] = (bf16_t)v.z; p[3] = (bf16_t)v.w;
      dst[idx] = p;
    }
  } else {
    int rr = row - IDIM * RDIM;  // flat (c*32 + w)
    const float4* src = (const float4*)(caps + (size_t)rr * DDIM);
    bf16x4* dst = (bf16x4*)(capsb + (size_t)rr * DDIM);
    float ss = 0.f;
#pragma unroll
    for (int j = 0; j < 4; ++j) {
      int idx = j * 64 + ln;
      float4 v = src[idx];
      ss += v.x * v.x + v.y * v.y + v.z * v.z + v.w * v.w;
      bf16x4 p;
      p[0] = (bf16_t)v.x; p[1] = (bf16_t)v.y; p[2] = (bf16_t)v.z; p[3] = (bf16_t)v.w;
      dst[idx] = p;
    }
#pragma unroll
    for (int off = 32; off >= 1; off >>= 1) ss += __shfl_xor(ss, off, 64);
    if (ln == 0) capnorm[rr] = sqrtf(ss);  // fp32 norm (matches ref w1 exactly-ish)
  }
}

// =====================================================================
// Kernel 2: Gram matrices G[i][r][r'] = imgs[i,r] . imgs[i,r'] via MFMA.
// One block per i; M=N=48 (pad 36), K=1024 split 256/wave.
// =====================================================================
__global__ __launch_bounds__(256) void gram_kernel(
    const bf16_t* __restrict__ imgsb, float* __restrict__ G) {
  __shared__ float part[4][48][49];
  int i = blockIdx.x;
  int tid = threadIdx.x, wv = tid >> 6, ln = tid & 63;
  int l15 = ln & 15, qd = ln >> 4;
  const bf16_t* ib = imgsb + (size_t)i * RDIM * DDIM;

  bf16x8 zero8;
#pragma unroll
  for (int z = 0; z < 8; ++z) zero8[z] = (bf16_t)0.0f;

  f32x4 acc[3][3];
#pragma unroll
  for (int mt = 0; mt < 3; ++mt)
#pragma unroll
    for (int nt = 0; nt < 3; ++nt) {
      f32x4 zf = {0.f, 0.f, 0.f, 0.f};
      acc[mt][nt] = zf;
    }

  int kb = wv * 256 + qd * 8;
  for (int kk = 0; kk < 8; ++kk) {
    int k = kb + kk * 32;
    bf16x8 a[3];
    a[0] = *(const bf16x8*)(ib + (size_t)l15 * DDIM + k);
    a[1] = *(const bf16x8*)(ib + (size_t)(16 + l15) * DDIM + k);
    a[2] = (l15 < 4) ? *(const bf16x8*)(ib + (size_t)(32 + l15) * DDIM + k) : zero8;
#pragma unroll
    for (int mt = 0; mt < 3; ++mt)
#pragma unroll
      for (int nt = 0; nt < 3; ++nt)
        acc[mt][nt] = MFMA16(a[mt], a[nt], acc[mt][nt]);
  }
#pragma unroll
  for (int mt = 0; mt < 3; ++mt)
#pragma unroll
    for (int nt = 0; nt < 3; ++nt)
#pragma unroll
      for (int rg = 0; rg < 4; ++rg)
        part[wv][mt * 16 + qd * 4 + rg][nt * 16 + l15] = acc[mt][nt][rg];
  __syncthreads();
  for (int idx = tid; idx < RDIM * RDIM; idx += 256) {
    int r = idx / RDIM, r2 = idx % RDIM;
    G[(size_t)i * (RDIM * RDIM) + idx] =
        part[0][r][r2] + part[1][r][r2] + part[2][r][r2] + part[3][r][r2];
  }
}

// =====================================================================
// Kernel 3: main. One block per (c,i). raw tile via MFMA, fused epilogue.
// =====================================================================
__global__ __launch_bounds__(256) void main_kernel(
    const bf16_t* __restrict__ imgsb, const bf16_t* __restrict__ capsb,
    const float* __restrict__ G, const float* __restrict__ capnorm,
    const int* __restrict__ cap_lens, float* __restrict__ out) {
  __shared__ float part[4][32][ATS];  // K-split partials; part[0] -> raw
  __shared__ float attn[32][ATS];     // lr -> softmax weights
  __shared__ float Gs[36][36];
  __shared__ float psum[36][4];
  __shared__ float normw[36];
  __shared__ float Ssum[32];
  __shared__ float pbuf[32][12];

  int c = blockIdx.x, i = blockIdx.y;
  int tid = threadIdx.x, wv = tid >> 6, ln = tid & 63;
  int l15 = ln & 15, qd = ln >> 4;
  int clen = cap_lens[c];

  const bf16_t* cb = capsb + (size_t)c * WDIM * DDIM;
  const bf16_t* ib = imgsb + (size_t)i * RDIM * DDIM;

  bf16x8 zero8;
#pragma unroll
  for (int z = 0; z < 8; ++z) zero8[z] = (bf16_t)0.0f;

  // ---- Phase 1: raw[w, r] = caps . imgs, K-split across waves ----
  f32x4 acc[2][3];
#pragma unroll
  for (int mt = 0; mt < 2; ++mt)
#pragma unroll
    for (int nt = 0; nt < 3; ++nt) {
      f32x4 zf = {0.f, 0.f, 0.f, 0.f};
      acc[mt][nt] = zf;
    }
  int kb = wv * 256 + qd * 8;
  for (int kk = 0; kk < 8; ++kk) {
    int k = kb + kk * 32;
    bf16x8 a0 = *(const bf16x8*)(cb + (size_t)l15 * DDIM + k);
    bf16x8 a1 = *(const bf16x8*)(cb + (size_t)(16 + l15) * DDIM + k);
    bf16x8 b0 = *(const bf16x8*)(ib + (size_t)l15 * DDIM + k);
    bf16x8 b1 = *(const bf16x8*)(ib + (size_t)(16 + l15) * DDIM + k);
    bf16x8 b2 = (l15 < 4) ? *(const bf16x8*)(ib + (size_t)(32 + l15) * DDIM + k) : zero8;
    acc[0][0] = MFMA16(a0, b0, acc[0][0]);
    acc[0][1] = MFMA16(a0, b1, acc[0][1]);
    acc[0][2] = MFMA16(a0, b2, acc[0][2]);
    acc[1][0] = MFMA16(a1, b0, acc[1][0]);
    acc[1][1] = MFMA16(a1, b1, acc[1][1]);
    acc[1][2] = MFMA16(a1, b2, acc[1][2]);
  }
  // C/D layout (m89-verified): row(M) = qd*4+reg, col(N) = lane&15
#pragma unroll
  for (int mt = 0; mt < 2; ++mt)
#pragma unroll
    for (int nt = 0; nt < 3; ++nt)
#pragma unroll
      for (int rg = 0; rg < 4; ++rg)
        part[wv][mt * 16 + qd * 4 + rg][nt * 16 + l15] = acc[mt][nt][rg];

  // cooperative load of Gram into LDS (overlaps with other waves' MFMA)
  for (int idx = tid; idx < 36 * 36; idx += 256)
    (&Gs[0][0])[idx] = G[(size_t)i * (RDIM * RDIM) + idx];
  __syncthreads();

  // ---- Phase 2: reduce K-partials; leaky-relu + w-mask ----
  for (int idx = tid; idx < 32 * 48; idx += 256) {
    int m = idx / 48, n = idx % 48;
    float v = part[0][m][n] + part[1][m][n] + part[2][m][n] + part[3][m][n];
    part[0][m][n] = v;  // raw (pre-activation) kept for S
    float l = (v > 0.f) ? v : 0.1f * v;
    if (m >= clen || n >= 36) l = 0.f;
    attn[m][n] = l;
  }
  __syncthreads();

  // ---- Phase 3: norm over w per column r ----
  if (tid < 144) {
    int n = tid >> 2, q = tid & 3;
    float s = 0.f;
#pragma unroll
    for (int mm = 0; mm < 8; ++mm) {
      float t = attn[q * 8 + mm][n];
      s += t * t;
    }
    psum[n][q] = s;
  }
  __syncthreads();
  if (tid < 36)
    normw[tid] = sqrtf(psum[tid][0] + psum[tid][1] + psum[tid][2] + psum[tid][3]) + EPSF;
  __syncthreads();

  // ---- Phase 4: softmax over r per row w (8 lanes/row) + S = sum attn*raw ----
  {
    int m = tid >> 3, j = tid & 7;
    float vals[5];
    float lmax = -1e30f;
#pragma unroll
    for (int kq = 0; kq < 5; ++kq) {
      int n = j + kq * 8;
      float v = (n < 36) ? (SMOOTH * attn[m][n] / normw[n]) : -1e30f;
      vals[kq] = v;
      lmax = fmaxf(lmax, v);
    }
#pragma unroll
    for (int off = 1; off < 8; off <<= 1) lmax = fmaxf(lmax, __shfl_xor(lmax, off, 64));
    float lsum = 0.f;
#pragma unroll
    for (int kq = 0; kq < 5; ++kq) {
      float e = (vals[kq] > -1e29f) ? __expf(vals[kq] - lmax) : 0.f;
      vals[kq] = e;
      lsum += e;
    }
#pragma unroll
    for (int off = 1; off < 8; off <<= 1) lsum += __shfl_xor(lsum, off, 64);
    float inv = 1.0f / lsum;
    float sacc = 0.f;
#pragma unroll
    for (int kq = 0; kq < 5; ++kq) {
      int n = j + kq * 8;
      if (n < 36) {
        float a = vals[kq] * inv;
        attn[m][n] = a;               // overwrite with softmax weight
        sacc += a * part[0][m][n];    // caps . wctx accumulation
      }
    }
#pragma unroll
    for (int off = 1; off < 8; off <<= 1) sacc += __shfl_xor(sacc, off, 64);
    if (j == 0) Ssum[m] = sacc;
  }
  __syncthreads();

  // ---- Phase 5: n2[m] = a^T G a  via float4 (32 rows x 9 quads) ----
  for (int idx = tid; idx < 32 * 9; idx += 256) {
    int m = idx / 9, q = idx % 9;
    f32x4 vacc = {0.f, 0.f, 0.f, 0.f};
    for (int r = 0; r < 36; ++r) {
      float a = attn[m][r];
      f32x4 g = *(const f32x4*)&Gs[r][q * 4];
      vacc += g * a;
    }
    f32x4 a4 = *(const f32x4*)&attn[m][q * 4];
    f32x4 pr = vacc * a4;
    pbuf[m][q] = pr[0] + pr[1] + pr[2] + pr[3];
  }
  __syncthreads();

  // ---- Phase 6: final sim + mask + store (transposed out[i][c][w]) ----
  if (tid < 32) {
    int m = tid;
    float n2 = 0.f;
#pragma unroll
    for (int q = 0; q < 9; ++q) n2 += pbuf[m][q];
    n2 = fmaxf(n2, 0.f);
    float nrm = sqrtf(n2);
    float den = nrm + EPSF;          // ref: wctx /= (||wctx|| + eps)
    float w12 = Ssum[m] / den;
    float w2 = nrm / den;
    float w1 = capnorm[c * WDIM + m];
    float sim = w12 / fmaxf(w1 * w2, EPSF);
    if (m >= clen) sim = -1.0f;
    out[((size_t)i * CDIM + c) * WDIM + m] = sim;
  }
}

// =====================================================================
extern "C" void kernel_launch(void* const* d_in, const int* in_sizes, int n_in,
                              void* d_out, int out_size, void* d_ws, size_t ws_size,
                              hipStream_t stream) {
  const float* imgs = (const float*)d_in[0];
  const float* caps = (const float*)d_in[1];
  // d_in[2] = img_lens (unused by the reference math)
  const int* cap_lens = (const int*)d_in[3];
  float* out = (float*)d_out;

  char* ws = (char*)d_ws;
  bf16_t* imgsb = (bf16_t*)(ws + IMGSB_OFF);
  bf16_t* capsb = (bf16_t*)(ws + CAPSB_OFF);
  float* G = (float*)(ws + G_OFF);
  float* capnorm = (float*)(ws + CAPN_OFF);

  prep_kernel<<<(IDIM * RDIM + CDIM * WDIM) / 4, 256, 0, stream>>>(imgs, caps, imgsb, capsb, capnorm);
  gram_kernel<<<IDIM, 256, 0, stream>>>(imgsb, G);
  main_kernel<<<dim3(CDIM, IDIM), 256, 0, stream>>>(imgsb, capsb, G, capnorm, cap_lens, out);
}

// Round 2
// 135.923 us; speedup vs baseline: 1.1715x; 1.1715x over previous
//
#include <hip/hip_runtime.h>
#include <hip/hip_bf16.h>

#define IDIM 64
#define RDIM 36
#define DDIM 1024
#define CDIM 64
#define WDIM 32
#define SMOOTH 9.0f
#define EPSF 1e-8f
#define ATS 52   // LDS row stride for 48-wide tiles: float4-aligned, conflict-light

typedef __bf16 bf16_t;
typedef __bf16 bf16x8 __attribute__((ext_vector_type(8)));
typedef float f32x4 __attribute__((ext_vector_type(4)));

#define MFMA16(a, b, c) __builtin_amdgcn_mfma_f32_16x16x32_bf16((a), (b), (c), 0, 0, 0)

// ---------- workspace layout (bytes) ----------
// imgsB: fragment-permuted imgs, rows padded to 48 with zeros.
//   elem offset = ((((i*4+wv)*8+kk)*3+nt)*64 + lane)*8 ; lane=(qd*16+l15)
//   holds imgs[i][nt*16+l15][wv*256+kk*32+qd*8 .. +7]
// capsA: fragment-permuted caps.
//   elem offset = ((((c*4+wv)*8+kk)*2+mt)*64 + lane)*8
#define IMGSB_OFF 0
#define IMGSB_BYTES (IDIM * 4 * 8 * 3 * 512 * 2)            // 6 MB
#define CAPSA_OFF (IMGSB_OFF + IMGSB_BYTES)
#define CAPSA_BYTES (CDIM * 4 * 8 * 2 * 512 * 2)            // 4 MB
#define G_OFF     (CAPSA_OFF + CAPSA_BYTES)
#define G_BYTES   (IDIM * RDIM * RDIM * 4)
#define CAPN_OFF  (G_OFF + G_BYTES)

// =====================================================================
// Kernel 1: fp32 -> bf16 fragment-permute for imgs & caps, caps norms,
// zero-fill of imgs pad rows 36..47. One wave per unit.
//   units [0,2304): imgs rows  [2304,4352): caps rows  [4352,6400): zerofill
// =====================================================================
__global__ __launch_bounds__(256) void prep_kernel(
    const float* __restrict__ imgs, const float* __restrict__ caps,
    bf16_t* __restrict__ imgsB, bf16_t* __restrict__ capsA,
    float* __restrict__ capnorm) {
  int wv = threadIdx.x >> 6, ln = threadIdx.x & 63;
  int unit = blockIdx.x * 4 + wv;
  if (unit < IDIM * RDIM) {
    int i = unit / RDIM, r = unit % RDIM;
    int nt = r >> 4, l15 = r & 15;
    const float* src = imgs + (size_t)unit * DDIM;
#pragma unroll
    for (int itr = 0; itr < 2; ++itr) {
      int ch = itr * 64 + ln;           // 0..127 k-chunks of 8
      int k = ch * 8;
      int wvk = ch >> 5, kk = (ch >> 2) & 7, qd = ch & 3;
      float4 v0 = *(const float4*)(src + k);
      float4 v1 = *(const float4*)(src + k + 4);
      bf16x8 p;
      p[0] = (bf16_t)v0.x; p[1] = (bf16_t)v0.y; p[2] = (bf16_t)v0.z; p[3] = (bf16_t)v0.w;
      p[4] = (bf16_t)v1.x; p[5] = (bf16_t)v1.y; p[6] = (bf16_t)v1.z; p[7] = (bf16_t)v1.w;
      size_t dst = ((((size_t)(i * 4 + wvk) * 8 + kk) * 3 + nt) * 64 + qd * 16 + l15) * 8;
      *(bf16x8*)(imgsB + dst) = p;
    }
  } else if (unit < IDIM * RDIM + CDIM * WDIM) {
    int rr = unit - IDIM * RDIM;        // c*32 + w
    int mt = (rr & 31) >> 4, l15 = rr & 15;
    int c = rr >> 5;
    const float* src = caps + (size_t)rr * DDIM;
    float ss = 0.f;
#pragma unroll
    for (int itr = 0; itr < 2; ++itr) {
      int ch = itr * 64 + ln;
      int k = ch * 8;
      int wvk = ch >> 5, kk = (ch >> 2) & 7, qd = ch & 3;
      float4 v0 = *(const float4*)(src + k);
      float4 v1 = *(const float4*)(src + k + 4);
      ss += v0.x * v0.x + v0.y * v0.y + v0.z * v0.z + v0.w * v0.w;
      ss += v1.x * v1.x + v1.y * v1.y + v1.z * v1.z + v1.w * v1.w;
      bf16x8 p;
      p[0] = (bf16_t)v0.x; p[1] = (bf16_t)v0.y; p[2] = (bf16_t)v0.z; p[3] = (bf16_t)v0.w;
      p[4] = (bf16_t)v1.x; p[5] = (bf16_t)v1.y; p[6] = (bf16_t)v1.z; p[7] = (bf16_t)v1.w;
      size_t dst = ((((size_t)(c * 4 + wvk) * 8 + kk) * 2 + mt) * 64 + qd * 16 + l15) * 8;
      *(bf16x8*)(capsA + dst) = p;
    }
#pragma unroll
    for (int off = 32; off >= 1; off >>= 1) ss += __shfl_xor(ss, off, 64);
    if (ln == 0) capnorm[rr] = sqrtf(ss);
  } else {
    int z = unit - (IDIM * RDIM + CDIM * WDIM);  // i*32 + wvk*8 + kk
    int i = z >> 5, wvk = (z >> 3) & 3, kk = z & 7;
    if ((ln & 15) >= 4) {                        // pad rows 36..47 (nt=2, l15>=4)
      bf16x8 zz;
#pragma unroll
      for (int q = 0; q < 8; ++q) zz[q] = (bf16_t)0.0f;
      size_t dst = ((((size_t)(i * 4 + wvk) * 8 + kk) * 3 + 2) * 64 + ln) * 8;
      *(bf16x8*)(imgsB + dst) = zz;
    }
  }
}

// =====================================================================
// Kernel 2: Gram G[i][r][r'] = imgs[i,r].imgs[i,r'] via MFMA, coalesced
// fragment loads from imgsB (pad rows are zero in memory).
// =====================================================================
__global__ __launch_bounds__(256) void gram_kernel(
    const bf16_t* __restrict__ imgsB, float* __restrict__ G) {
  __shared__ float part[4][48][49];
  int i = blockIdx.x;
  int tid = threadIdx.x, wv = tid >> 6, ln = tid & 63;
  int l15 = ln & 15, qd = ln >> 4;
  const bf16_t* base = imgsB + (size_t)(i * 4 + wv) * 8 * 3 * 512;

  f32x4 acc[3][3];
#pragma unroll
  for (int mt = 0; mt < 3; ++mt)
#pragma unroll
    for (int nt = 0; nt < 3; ++nt) {
      f32x4 zf = {0.f, 0.f, 0.f, 0.f};
      acc[mt][nt] = zf;
    }
#pragma unroll
  for (int kk = 0; kk < 8; ++kk) {
    bf16x8 a[3];
#pragma unroll
    for (int nt = 0; nt < 3; ++nt)
      a[nt] = *(const bf16x8*)(base + ((size_t)(kk * 3 + nt) * 64 + ln) * 8);
#pragma unroll
    for (int mt = 0; mt < 3; ++mt)
#pragma unroll
      for (int nt = 0; nt < 3; ++nt)
        acc[mt][nt] = MFMA16(a[mt], a[nt], acc[mt][nt]);
  }
#pragma unroll
  for (int mt = 0; mt < 3; ++mt)
#pragma unroll
    for (int nt = 0; nt < 3; ++nt)
#pragma unroll
      for (int rg = 0; rg < 4; ++rg)
        part[wv][mt * 16 + qd * 4 + rg][nt * 16 + l15] = acc[mt][nt][rg];
  __syncthreads();
  for (int idx = tid; idx < RDIM * RDIM; idx += 256) {
    int r = idx / RDIM, r2 = idx % RDIM;
    G[(size_t)i * (RDIM * RDIM) + idx] =
        part[0][r][r2] + part[1][r][r2] + part[2][r][r2] + part[3][r][r2];
  }
}

// =====================================================================
// Kernel 3: main. Block = (c, image-group of 8). grid 512 = 2 blocks/CU,
// single batch. A-frags pinned in regs (reused 8x); B-frags for i+1
// prefetched during epilogue of i. ig = blockIdx&7 -> XCD-local imgs.
// =====================================================================
__global__ __launch_bounds__(256, 2) void main_kernel(
    const bf16_t* __restrict__ capsA, const bf16_t* __restrict__ imgsB,
    const float* __restrict__ G, const float* __restrict__ capnorm,
    const int* __restrict__ cap_lens, float* __restrict__ out) {
  __shared__ float part[4][32][ATS];  // K-split partials; part[0] -> raw
  __shared__ float attn[32][ATS];
  __shared__ float Gs[36][36];
  __shared__ float psum[36][4];
  __shared__ float normw[36];
  __shared__ float Ssum[32];
  __shared__ float pbuf[32][12];

  int bx = blockIdx.x;
  int ig = bx & 7, c = bx >> 3;       // same ig -> same XCD (round-robin)
  int tid = threadIdx.x, wv = tid >> 6, ln = tid & 63;
  int l15 = ln & 15, qd = ln >> 4;
  int clen = cap_lens[c];
  int i0 = ig * 8;

  // ---- pin A fragments (caps tile, this wave's K-slice) ----
  const bf16_t* Ab = capsA + (size_t)(c * 4 + wv) * 8 * 2 * 512;
  bf16x8 A0[8], A1[8];
#pragma unroll
  for (int kk = 0; kk < 8; ++kk) {
    A0[kk] = *(const bf16x8*)(Ab + ((size_t)(kk * 2 + 0) * 64 + ln) * 8);
    A1[kk] = *(const bf16x8*)(Ab + ((size_t)(kk * 2 + 1) * 64 + ln) * 8);
  }
  // ---- first image's B fragments ----
  bf16x8 B0[8], B1[8], B2[8];
  {
    const bf16_t* Bb = imgsB + (size_t)(i0 * 4 + wv) * 8 * 3 * 512;
#pragma unroll
    for (int kk = 0; kk < 8; ++kk) {
      B0[kk] = *(const bf16x8*)(Bb + ((size_t)(kk * 3 + 0) * 64 + ln) * 8);
      B1[kk] = *(const bf16x8*)(Bb + ((size_t)(kk * 3 + 1) * 64 + ln) * 8);
      B2[kk] = *(const bf16x8*)(Bb + ((size_t)(kk * 3 + 2) * 64 + ln) * 8);
    }
  }

  for (int it = 0; it < 8; ++it) {
    int i = i0 + it;
    // ---- Phase 1: MFMA, K-split 256/wave ----
    f32x4 acc[2][3];
#pragma unroll
    for (int mt = 0; mt < 2; ++mt)
#pragma unroll
      for (int nt = 0; nt < 3; ++nt) {
        f32x4 zf = {0.f, 0.f, 0.f, 0.f};
        acc[mt][nt] = zf;
      }
#pragma unroll
    for (int kk = 0; kk < 8; ++kk) {
      acc[0][0] = MFMA16(A0[kk], B0[kk], acc[0][0]);
      acc[0][1] = MFMA16(A0[kk], B1[kk], acc[0][1]);
      acc[0][2] = MFMA16(A0[kk], B2[kk], acc[0][2]);
      acc[1][0] = MFMA16(A1[kk], B0[kk], acc[1][0]);
      acc[1][1] = MFMA16(A1[kk], B1[kk], acc[1][1]);
      acc[1][2] = MFMA16(A1[kk], B2[kk], acc[1][2]);
    }
    // C/D layout: row(M)=qd*4+rg, col(N)=l15
#pragma unroll
    for (int mt = 0; mt < 2; ++mt)
#pragma unroll
      for (int nt = 0; nt < 3; ++nt)
#pragma unroll
        for (int rg = 0; rg < 4; ++rg)
          part[wv][mt * 16 + qd * 4 + rg][nt * 16 + l15] = acc[mt][nt][rg];
    // Gram for this i into LDS
    for (int idx = tid; idx < 36 * 36; idx += 256)
      (&Gs[0][0])[idx] = G[(size_t)i * (RDIM * RDIM) + idx];
    __syncthreads();

    // ---- prefetch next image's B (hidden behind epilogue) ----
    if (it < 7) {
      const bf16_t* Bn = imgsB + (size_t)((i + 1) * 4 + wv) * 8 * 3 * 512;
#pragma unroll
      for (int kk = 0; kk < 8; ++kk) {
        B0[kk] = *(const bf16x8*)(Bn + ((size_t)(kk * 3 + 0) * 64 + ln) * 8);
        B1[kk] = *(const bf16x8*)(Bn + ((size_t)(kk * 3 + 1) * 64 + ln) * 8);
        B2[kk] = *(const bf16x8*)(Bn + ((size_t)(kk * 3 + 2) * 64 + ln) * 8);
      }
    }

    // ---- Phase 2: reduce K-partials; leaky-relu + w-mask ----
    for (int idx = tid; idx < 32 * 48; idx += 256) {
      int m = idx / 48, n = idx % 48;
      float v = part[0][m][n] + part[1][m][n] + part[2][m][n] + part[3][m][n];
      part[0][m][n] = v;  // raw kept for S
      float l = (v > 0.f) ? v : 0.1f * v;
      if (m >= clen || n >= 36) l = 0.f;
      attn[m][n] = l;
    }
    __syncthreads();

    // ---- Phase 3: norm over w per column r ----
    if (tid < 144) {
      int n = tid >> 2, q = tid & 3;
      float s = 0.f;
#pragma unroll
      for (int mm = 0; mm < 8; ++mm) {
        float t = attn[q * 8 + mm][n];
        s += t * t;
      }
      psum[n][q] = s;
    }
    __syncthreads();
    if (tid < 36)
      normw[tid] = sqrtf(psum[tid][0] + psum[tid][1] + psum[tid][2] + psum[tid][3]) + EPSF;
    __syncthreads();

    // ---- Phase 4: softmax over r per row w (8 lanes/row) + S ----
    {
      int m = tid >> 3, j = tid & 7;
      float vals[5];
      float lmax = -1e30f;
#pragma unroll
      for (int kq = 0; kq < 5; ++kq) {
        int n = j + kq * 8;
        float v = (n < 36) ? (SMOOTH * attn[m][n] / normw[n]) : -1e30f;
        vals[kq] = v;
        lmax = fmaxf(lmax, v);
      }
#pragma unroll
      for (int off = 1; off < 8; off <<= 1) lmax = fmaxf(lmax, __shfl_xor(lmax, off, 64));
      float lsum = 0.f;
#pragma unroll
      for (int kq = 0; kq < 5; ++kq) {
        float e = (vals[kq] > -1e29f) ? __expf(vals[kq] - lmax) : 0.f;
        vals[kq] = e;
        lsum += e;
      }
#pragma unroll
      for (int off = 1; off < 8; off <<= 1) lsum += __shfl_xor(lsum, off, 64);
      float inv = 1.0f / lsum;
      float sacc = 0.f;
#pragma unroll
      for (int kq = 0; kq < 5; ++kq) {
        int n = j + kq * 8;
        if (n < 36) {
          float a = vals[kq] * inv;
          attn[m][n] = a;
          sacc += a * part[0][m][n];
        }
      }
#pragma unroll
      for (int off = 1; off < 8; off <<= 1) sacc += __shfl_xor(sacc, off, 64);
      if (j == 0) Ssum[m] = sacc;
    }
    __syncthreads();

    // ---- Phase 5: n2[m] = a^T G a via float4 ----
    for (int idx = tid; idx < 32 * 9; idx += 256) {
      int m = idx / 9, q = idx % 9;
      f32x4 vacc = {0.f, 0.f, 0.f, 0.f};
#pragma unroll 4
      for (int r = 0; r < 36; ++r) {
        float a = attn[m][r];
        f32x4 g = *(const f32x4*)&Gs[r][q * 4];
        vacc += g * a;
      }
      f32x4 a4 = *(const f32x4*)&attn[m][q * 4];
      f32x4 pr = vacc * a4;
      pbuf[m][q] = pr[0] + pr[1] + pr[2] + pr[3];
    }
    __syncthreads();

    // ---- Phase 6: final sim + mask + store out[i][c][w] ----
    if (tid < 32) {
      int m = tid;
      float n2 = 0.f;
#pragma unroll
      for (int q = 0; q < 9; ++q) n2 += pbuf[m][q];
      n2 = fmaxf(n2, 0.f);
      float nrm = sqrtf(n2);
      float den = nrm + EPSF;
      float w12 = Ssum[m] / den;
      float w2 = nrm / den;
      float w1 = capnorm[c * WDIM + m];
      float sim = w12 / fmaxf(w1 * w2, EPSF);
      if (m >= clen) sim = -1.0f;
      out[((size_t)i * CDIM + c) * WDIM + m] = sim;
    }
    __syncthreads();  // protect part/attn/Gs before next iteration
  }
}

// =====================================================================
extern "C" void kernel_launch(void* const* d_in, const int* in_sizes, int n_in,
                              void* d_out, int out_size, void* d_ws, size_t ws_size,
                              hipStream_t stream) {
  const float* imgs = (const float*)d_in[0];
  const float* caps = (const float*)d_in[1];
  const int* cap_lens = (const int*)d_in[3];
  float* out = (float*)d_out;

  char* ws = (char*)d_ws;
  bf16_t* imgsB = (bf16_t*)(ws + IMGSB_OFF);
  bf16_t* capsA = (bf16_t*)(ws + CAPSA_OFF);
  float* G = (float*)(ws + G_OFF);
  float* capnorm = (float*)(ws + CAPN_OFF);

  // units: 2304 imgs rows + 2048 caps rows + 2048 zero-fill = 6400 waves
  prep_kernel<<<1600, 256, 0, stream>>>(imgs, caps, imgsB, capsA, capnorm);
  gram_kernel<<<IDIM, 256, 0, stream>>>(imgsB, G);
  main_kernel<<<512, 256, 0, stream>>>(capsA, imgsB, G, capnorm, cap_lens, out);
}

// Round 3
// 108.008 us; speedup vs baseline: 1.4742x; 1.2584x over previous
//
#include <hip/hip_runtime.h>
#include <hip/hip_bf16.h>

#define IDIM 64
#define RDIM 36
#define DDIM 1024
#define CDIM 64
#define WDIM 32
#define SMOOTH 9.0f
#define EPSF 1e-8f

typedef __bf16 bf16_t;
typedef __bf16 bf16x8 __attribute__((ext_vector_type(8)));
typedef float f32x4 __attribute__((ext_vector_type(4)));

#define MFMA16(a, b, c) __builtin_amdgcn_mfma_f32_16x16x32_bf16((a), (b), (c), 0, 0, 0)

// ---------- workspace layout (bytes) ----------
// imgsB: fragment-permuted imgs, rows padded to 48 with zeros.
//   elem offset = ((((i*4+wvk)*8+kk)*3+nt)*64 + lane)*8 ; lane=(qd*16+l15)
//   holds imgs[i][nt*16+l15][wvk*256+kk*32+qd*8 .. +7]
// capsA: same but 2 mt tiles:  ((((c*4+wvk)*8+kk)*2+mt)*64 + lane)*8
// Gfrag: bf16 B-layout frags of Gram, per i: [(kk*3+nt)*64+lane]*8, kk in {0,1} covers k 0..63 (zero-padded)
#define IMGSB_OFF 0
#define IMGSB_BYTES (IDIM * 4 * 8 * 3 * 512 * 2)            // 6 MB
#define CAPSA_OFF (IMGSB_OFF + IMGSB_BYTES)
#define CAPSA_BYTES (CDIM * 4 * 8 * 2 * 512 * 2)            // 4 MB
#define GF_OFF    (CAPSA_OFF + CAPSA_BYTES)
#define GF_BYTES  (IDIM * 384 * 8 * 2)                      // 384 KB
#define CAPN_OFF  (GF_OFF + GF_BYTES)

// =====================================================================
// Kernel 1: fp32 -> bf16 fragment-permute for imgs & caps, caps norms,
// zero-fill of imgs pad rows 36..47. One wave per unit.
// =====================================================================
__global__ __launch_bounds__(256) void prep_kernel(
    const float* __restrict__ imgs, const float* __restrict__ caps,
    bf16_t* __restrict__ imgsB, bf16_t* __restrict__ capsA,
    float* __restrict__ capnorm) {
  int wv = threadIdx.x >> 6, ln = threadIdx.x & 63;
  int unit = blockIdx.x * 4 + wv;
  if (unit < IDIM * RDIM) {
    int i = unit / RDIM, r = unit % RDIM;
    int nt = r >> 4, l15 = r & 15;
    const float* src = imgs + (size_t)unit * DDIM;
#pragma unroll
    for (int itr = 0; itr < 2; ++itr) {
      int ch = itr * 64 + ln;           // 0..127 k-chunks of 8
      int k = ch * 8;
      int wvk = ch >> 5, kk = (ch >> 2) & 7, qd = ch & 3;
      float4 v0 = *(const float4*)(src + k);
      float4 v1 = *(const float4*)(src + k + 4);
      bf16x8 p;
      p[0] = (bf16_t)v0.x; p[1] = (bf16_t)v0.y; p[2] = (bf16_t)v0.z; p[3] = (bf16_t)v0.w;
      p[4] = (bf16_t)v1.x; p[5] = (bf16_t)v1.y; p[6] = (bf16_t)v1.z; p[7] = (bf16_t)v1.w;
      size_t dst = ((((size_t)(i * 4 + wvk) * 8 + kk) * 3 + nt) * 64 + qd * 16 + l15) * 8;
      *(bf16x8*)(imgsB + dst) = p;
    }
  } else if (unit < IDIM * RDIM + CDIM * WDIM) {
    int rr = unit - IDIM * RDIM;        // c*32 + w
    int mt = (rr & 31) >> 4, l15 = rr & 15;
    int c = rr >> 5;
    const float* src = caps + (size_t)rr * DDIM;
    float ss = 0.f;
#pragma unroll
    for (int itr = 0; itr < 2; ++itr) {
      int ch = itr * 64 + ln;
      int k = ch * 8;
      int wvk = ch >> 5, kk = (ch >> 2) & 7, qd = ch & 3;
      float4 v0 = *(const float4*)(src + k);
      float4 v1 = *(const float4*)(src + k + 4);
      ss += v0.x * v0.x + v0.y * v0.y + v0.z * v0.z + v0.w * v0.w;
      ss += v1.x * v1.x + v1.y * v1.y + v1.z * v1.z + v1.w * v1.w;
      bf16x8 p;
      p[0] = (bf16_t)v0.x; p[1] = (bf16_t)v0.y; p[2] = (bf16_t)v0.z; p[3] = (bf16_t)v0.w;
      p[4] = (bf16_t)v1.x; p[5] = (bf16_t)v1.y; p[6] = (bf16_t)v1.z; p[7] = (bf16_t)v1.w;
      size_t dst = ((((size_t)(c * 4 + wvk) * 8 + kk) * 2 + mt) * 64 + qd * 16 + l15) * 8;
      *(bf16x8*)(capsA + dst) = p;
    }
#pragma unroll
    for (int off = 32; off >= 1; off >>= 1) ss += __shfl_xor(ss, off, 64);
    if (ln == 0) capnorm[rr] = sqrtf(ss);
  } else {
    int z = unit - (IDIM * RDIM + CDIM * WDIM);  // i*32 + wvk*8 + kk
    int i = z >> 5, wvk = (z >> 3) & 3, kk = z & 7;
    if ((ln & 15) >= 4) {                        // pad rows 36..47 (nt=2, l15>=4)
      bf16x8 zz;
#pragma unroll
      for (int q = 0; q < 8; ++q) zz[q] = (bf16_t)0.0f;
      size_t dst = ((((size_t)(i * 4 + wvk) * 8 + kk) * 3 + 2) * 64 + ln) * 8;
      *(bf16x8*)(imgsB + dst) = zz;
    }
  }
}

// =====================================================================
// Kernel 2: Gram G[i] via MFMA from imgsB; emit bf16 B-layout frags
// (K padded to 64 with zeros) for the main kernel's n2 = a^T G a MFMA.
// =====================================================================
__global__ __launch_bounds__(256) void gram_kernel(
    const bf16_t* __restrict__ imgsB, bf16_t* __restrict__ Gfrag) {
  __shared__ float part[4][48][49];
  int i = blockIdx.x;
  int tid = threadIdx.x, wv = tid >> 6, ln = tid & 63;
  int l15 = ln & 15, qd = ln >> 4;
  const bf16_t* base = imgsB + (size_t)(i * 4 + wv) * 8 * 3 * 512;

  f32x4 acc[3][3];
#pragma unroll
  for (int mt = 0; mt < 3; ++mt)
#pragma unroll
    for (int nt = 0; nt < 3; ++nt) {
      f32x4 zf = {0.f, 0.f, 0.f, 0.f};
      acc[mt][nt] = zf;
    }
#pragma unroll
  for (int kk = 0; kk < 8; ++kk) {
    bf16x8 a[3];
#pragma unroll
    for (int nt = 0; nt < 3; ++nt)
      a[nt] = *(const bf16x8*)(base + ((size_t)(kk * 3 + nt) * 64 + ln) * 8);
#pragma unroll
    for (int mt = 0; mt < 3; ++mt)
#pragma unroll
      for (int nt = 0; nt < 3; ++nt)
        acc[mt][nt] = MFMA16(a[mt], a[nt], acc[mt][nt]);
  }
#pragma unroll
  for (int mt = 0; mt < 3; ++mt)
#pragma unroll
    for (int nt = 0; nt < 3; ++nt)
#pragma unroll
      for (int rg = 0; rg < 4; ++rg)
        part[wv][mt * 16 + qd * 4 + rg][nt * 16 + l15] = acc[mt][nt][rg];
  __syncthreads();
  // build bf16 B-layout fragments: lane(qd,l15) holds G[k=kk*32+qd*8+j][n=nt*16+l15]
  for (int idx = tid; idx < 384; idx += 256) {
    int kk = idx / 192;
    int rem = idx - kk * 192;
    int nt = rem >> 6, lnn = rem & 63;
    int qd2 = lnn >> 4, l152 = lnn & 15;
    int n = nt * 16 + l152;
    bf16x8 pk;
#pragma unroll
    for (int j = 0; j < 8; ++j) {
      int k = kk * 32 + qd2 * 8 + j;
      float v = (k < 48) ? (part[0][k][n] + part[1][k][n] + part[2][k][n] + part[3][k][n]) : 0.f;
      pk[j] = (bf16_t)v;
    }
    *(bf16x8*)(Gfrag + ((size_t)i * 384 + idx) * 8) = pk;
  }
}

// =====================================================================
// Kernel 3: main — ONE WAVE PER (c,i) TILE, zero barriers.
// Wave: full-K GEMM (32x48 raw tile in 24 acc regs), then wave-level
// epilogue: shuffles for w-norm/softmax/S, MFMA for n2 = a^T G a.
// grid 1024 blocks x 4 waves; block's 4 waves share c (L1 A-reuse),
// i grouped by XCD (bx&7) so each XCD's 8 images are L2-resident.
// =====================================================================
__global__ __launch_bounds__(256, 3) void main_kernel(
    const bf16_t* __restrict__ capsA, const bf16_t* __restrict__ imgsB,
    const bf16_t* __restrict__ Gfrag, const float* __restrict__ capnorm,
    const int* __restrict__ cap_lens, float* __restrict__ out) {
  __shared__ __align__(16) bf16_t attnS[4][32 * 72];  // per-wave scratch, no sharing

  int bx = blockIdx.x;
  int wv = threadIdx.x >> 6, ln = threadIdx.x & 63;
  int l15 = ln & 15, qd = ln >> 4;
  int xcd = bx & 7, t = bx >> 3;
  int c = t & 63, ih = t >> 6;
  int i = xcd * 8 + ih * 4 + wv;
  int clen = cap_lens[c];

  const bf16_t* Ab = capsA + (size_t)c * (4 * 8 * 2 * 512);
  const bf16_t* Bb = imgsB + (size_t)i * (4 * 8 * 3 * 512);

  // ---- GEMM: raw[m][n] over full K=1024, 32 steps of 6 MFMA ----
  f32x4 acc[2][3];
#pragma unroll
  for (int mt = 0; mt < 2; ++mt)
#pragma unroll
    for (int nt = 0; nt < 3; ++nt) {
      f32x4 zf = {0.f, 0.f, 0.f, 0.f};
      acc[mt][nt] = zf;
    }
#pragma unroll 4
  for (int s = 0; s < 32; ++s) {
    const bf16_t* ap = Ab + (size_t)s * 1024 + ln * 8;
    const bf16_t* bp = Bb + (size_t)s * 1536 + ln * 8;
    bf16x8 a0 = *(const bf16x8*)(ap);
    bf16x8 a1 = *(const bf16x8*)(ap + 512);
    bf16x8 b0 = *(const bf16x8*)(bp);
    bf16x8 b1 = *(const bf16x8*)(bp + 512);
    bf16x8 b2 = *(const bf16x8*)(bp + 1024);
    acc[0][0] = MFMA16(a0, b0, acc[0][0]);
    acc[0][1] = MFMA16(a0, b1, acc[0][1]);
    acc[0][2] = MFMA16(a0, b2, acc[0][2]);
    acc[1][0] = MFMA16(a1, b0, acc[1][0]);
    acc[1][1] = MFMA16(a1, b1, acc[1][1]);
    acc[1][2] = MFMA16(a1, b2, acc[1][2]);
  }

  // ---- prefetch G frags + capnorm (latency hides behind softmax) ----
  const bf16_t* Gb = Gfrag + (size_t)i * 3072;
  bf16x8 ga[2][3];
#pragma unroll
  for (int kk = 0; kk < 2; ++kk)
#pragma unroll
    for (int nt = 0; nt < 3; ++nt)
      ga[kk][nt] = *(const bf16x8*)(Gb + ((size_t)(kk * 3 + nt) * 64 + ln) * 8);
  f32x4 cn0 = *(const f32x4*)(capnorm + c * 32 + qd * 4);
  f32x4 cn1 = *(const f32x4*)(capnorm + c * 32 + 16 + qd * 4);

  // ---- leaky-relu + masks (rows m>=clen, cols n>=36) ----
  float attnv[2][3][4];
#pragma unroll
  for (int mt = 0; mt < 2; ++mt)
#pragma unroll
    for (int nt = 0; nt < 3; ++nt) {
      bool padn = (nt == 2) && (l15 >= 4);
#pragma unroll
      for (int rg = 0; rg < 4; ++rg) {
        float v = acc[mt][nt][rg];
        float l = (v > 0.f) ? v : 0.1f * v;
        int m = mt * 16 + qd * 4 + rg;
        if (m >= clen || padn) l = 0.f;
        attnv[mt][nt][rg] = l;
      }
    }

  // ---- w-norm: sum over 32 rows per column (in-lane 8 + qd butterfly) ----
  float sinv[3];
#pragma unroll
  for (int nt = 0; nt < 3; ++nt) {
    float ns = 0.f;
#pragma unroll
    for (int mt = 0; mt < 2; ++mt)
#pragma unroll
      for (int rg = 0; rg < 4; ++rg) {
        float t2 = attnv[mt][nt][rg];
        ns += t2 * t2;
      }
    ns += __shfl_xor(ns, 16, 64);
    ns += __shfl_xor(ns, 32, 64);
    sinv[nt] = SMOOTH / (sqrtf(ns) + EPSF);
  }

  // ---- softmax over r per row (l15 butterfly) + S = sum attn*raw ----
  float Srow[2][4];
#pragma unroll
  for (int mt = 0; mt < 2; ++mt)
#pragma unroll
    for (int rg = 0; rg < 4; ++rg) {
      float z[3];
#pragma unroll
      for (int nt = 0; nt < 3; ++nt) {
        float v = attnv[mt][nt][rg] * sinv[nt];
        if (nt == 2 && l15 >= 4) v = -1e30f;
        z[nt] = v;
      }
      float mx = fmaxf(fmaxf(z[0], z[1]), z[2]);
#pragma unroll
      for (int off = 1; off < 16; off <<= 1) mx = fmaxf(mx, __shfl_xor(mx, off, 64));
      float e[3], es = 0.f;
#pragma unroll
      for (int nt = 0; nt < 3; ++nt) {
        e[nt] = __expf(z[nt] - mx);
        es += e[nt];
      }
#pragma unroll
      for (int off = 1; off < 16; off <<= 1) es += __shfl_xor(es, off, 64);
      float inv = 1.0f / es;
      float sac = 0.f;
#pragma unroll
      for (int nt = 0; nt < 3; ++nt) {
        float a = e[nt] * inv;
        attnv[mt][nt][rg] = a;
        sac += a * acc[mt][nt][rg];
      }
#pragma unroll
      for (int off = 1; off < 16; off <<= 1) sac += __shfl_xor(sac, off, 64);
      Srow[mt][rg] = sac;
    }

  // ---- stage attn to LDS (bf16, A-frag order), within-wave only ----
  bf16_t* as = &attnS[wv][0];
#pragma unroll
  for (int mt = 0; mt < 2; ++mt)
#pragma unroll
    for (int nt = 0; nt < 3; ++nt)
#pragma unroll
      for (int rg = 0; rg < 4; ++rg)
        as[(mt * 16 + qd * 4 + rg) * 72 + nt * 16 + l15] = (bf16_t)attnv[mt][nt][rg];
  {  // zero k in [48,64): lane zeroes 8 elems of row ln>>1
    bf16x8 z8;
#pragma unroll
    for (int q = 0; q < 8; ++q) z8[q] = (bf16_t)0.0f;
    *(bf16x8*)(as + (ln >> 1) * 72 + 48 + (ln & 1) * 8) = z8;
  }
  // read back as A-fragments
  bf16x8 fa[2][2];
#pragma unroll
  for (int mt = 0; mt < 2; ++mt)
#pragma unroll
    for (int kk = 0; kk < 2; ++kk)
      fa[mt][kk] = *(const bf16x8*)(as + (mt * 16 + l15) * 72 + kk * 32 + qd * 8);

  // ---- Y = attn * G via MFMA; n2[m] = sum Y .* attn ----
  f32x4 y[2][3];
#pragma unroll
  for (int mt = 0; mt < 2; ++mt)
#pragma unroll
    for (int nt = 0; nt < 3; ++nt) {
      f32x4 zf = {0.f, 0.f, 0.f, 0.f};
      y[mt][nt] = zf;
    }
#pragma unroll
  for (int kk = 0; kk < 2; ++kk)
#pragma unroll
    for (int mt = 0; mt < 2; ++mt)
#pragma unroll
      for (int nt = 0; nt < 3; ++nt)
        y[mt][nt] = MFMA16(fa[mt][kk], ga[kk][nt], y[mt][nt]);

  float n2row[2][4];
#pragma unroll
  for (int mt = 0; mt < 2; ++mt)
#pragma unroll
    for (int rg = 0; rg < 4; ++rg) {
      float nn = 0.f;
#pragma unroll
      for (int nt = 0; nt < 3; ++nt) nn += y[mt][nt][rg] * attnv[mt][nt][rg];
#pragma unroll
      for (int off = 1; off < 16; off <<= 1) nn += __shfl_xor(nn, off, 64);
      n2row[mt][rg] = nn;
    }

  // ---- final sim + store: lanes l15<2 write float4 each ----
  if (l15 < 2) {
    int mt = l15;
    f32x4 cn = mt ? cn1 : cn0;
    f32x4 o;
#pragma unroll
    for (int rg = 0; rg < 4; ++rg) {
      float n2v = fmaxf(n2row[mt][rg], 0.f);
      float nrm = sqrtf(n2v);
      float den = nrm + EPSF;
      float w12 = Srow[mt][rg] / den;
      float w2 = nrm / den;
      float sim = w12 / fmaxf(cn[rg] * w2, EPSF);
      int m = mt * 16 + qd * 4 + rg;
      if (m >= clen) sim = -1.0f;
      o[rg] = sim;
    }
    *(f32x4*)(out + ((size_t)i * CDIM + c) * WDIM + mt * 16 + qd * 4) = o;
  }
}

// =====================================================================
extern "C" void kernel_launch(void* const* d_in, const int* in_sizes, int n_in,
                              void* d_out, int out_size, void* d_ws, size_t ws_size,
                              hipStream_t stream) {
  const float* imgs = (const float*)d_in[0];
  const float* caps = (const float*)d_in[1];
  const int* cap_lens = (const int*)d_in[3];
  float* out = (float*)d_out;

  char* ws = (char*)d_ws;
  bf16_t* imgsB = (bf16_t*)(ws + IMGSB_OFF);
  bf16_t* capsA = (bf16_t*)(ws + CAPSA_OFF);
  bf16_t* Gfrag = (bf16_t*)(ws + GF_OFF);
  float* capnorm = (float*)(ws + CAPN_OFF);

  prep_kernel<<<1600, 256, 0, stream>>>(imgs, caps, imgsB, capsA, capnorm);
  gram_kernel<<<IDIM, 256, 0, stream>>>(imgsB, Gfrag);
  main_kernel<<<1024, 256, 0, stream>>>(capsA, imgsB, Gfrag, capnorm, cap_lens, out);
}